// Round 14
// baseline (456.784 us; speedup 1.0000x reference)
//
#include <hip/hip_runtime.h>
#include <math.h>

#define BB 8
#define HH 384
#define WW 384
#define NPAR 6
#define DEL 10
#define MAXIT 12
#define NACC 24
#define HWPIX (HH*WW)
#define NRT4 91                 // 4-row tiles covering rows 10..373 exactly
#define PITCH2 141              // staged I2 cols (140 used)
#define NR2 8                   // staged I2 rows
#define WS2C 140                // compile-time staging width (div -> magic mul)
#define KB_ 8                   // atomic buckets (blockIdx.x & 7)
#define SPS 32                  // doubles per (bucket,b) slot (256 B, line-padded)

typedef float vf4 __attribute__((ext_vector_type(4)));
typedef vf4 uvf4 __attribute__((aligned(4)));      // 4B-aligned global dwordx4
typedef float f2v __attribute__((ext_vector_type(2), aligned(4)));
typedef float lf4 __attribute__((ext_vector_type(4)));  // 16B-aligned (LDS)

__device__ __forceinline__ vf4 ldv4(const float* p) { return *(const uvf4*)p; }

// One-instruction staged-pixel load: dwordx4 covering this pixel's 3 floats.
// Tail guard: last pixel uses a shifted load to avoid a 4B OOB read.
__device__ __forceinline__ lf4 ldpx3(const float* __restrict__ Ib, int pixoff) {
    const int fo = pixoff * 3;
    if (fo + 4 <= HWPIX * 3) {
        vf4 v = ldv4(Ib + fo);
        return (lf4){v.x, v.y, v.z, 0.f};
    }
    vf4 v = ldv4(Ib + fo - 1);
    return (lf4){v.y, v.z, v.w, 0.f};
}

__device__ __forceinline__ float cubicw(float s) {
    s = fabsf(s);
    float s2 = s * s, s3 = s2 * s;
    float w1 = 1.5f * s3 - 2.5f * s2 + 1.0f;
    float w2 = -0.5f * s3 + 2.5f * s2 - 4.0f * s + 2.0f;
    return (s <= 1.0f) ? w1 : ((s < 2.0f) ? w2 : 0.0f);
}

// global fast-path bicubic (taps guaranteed in-bounds; drift fallback in k_iter)
__device__ __forceinline__ void bicubic3_fast(const float* __restrict__ Ib, double xg, double yg, float Iw[3]) {
    double fx = floor(xg), fy = floor(yg);
    float tx = (float)(xg - fx), ty = (float)(yg - fy);
    int xi = (int)fx, yi = (int)fy;
    float wx[4], wyv[4];
#pragma unroll
    for (int k = 0; k < 4; k++) { wx[k] = cubicw(tx - (float)(k - 1)); wyv[k] = cubicw(ty - (float)(k - 1)); }
    Iw[0] = 0.f; Iw[1] = 0.f; Iw[2] = 0.f;
    const float* base = Ib + (yi - 1) * (WW * 3) + (xi - 1) * 3;
#pragma unroll
    for (int j = 0; j < 4; j++) {
        const float* r = base + j * (WW * 3);
        vf4 v0 = ldv4(r), v1 = ldv4(r + 4), v2 = ldv4(r + 8);
        float r0 = fmaf(wx[0], v0.x, 0.f); r0 = fmaf(wx[1], v0.w, r0); r0 = fmaf(wx[2], v1.z, r0); r0 = fmaf(wx[3], v2.y, r0);
        float r1 = fmaf(wx[0], v0.y, 0.f); r1 = fmaf(wx[1], v1.x, r1); r1 = fmaf(wx[2], v1.w, r1); r1 = fmaf(wx[3], v2.z, r1);
        float r2 = fmaf(wx[0], v0.z, 0.f); r2 = fmaf(wx[1], v1.y, r2); r2 = fmaf(wx[2], v2.x, r2); r2 = fmaf(wx[3], v2.w, r2);
        Iw[0] = fmaf(wyv[j], r0, Iw[0]);
        Iw[1] = fmaf(wyv[j], r1, Iw[1]);
        Iw[2] = fmaf(wyv[j], r2, Iw[2]);
    }
}

// general bicubic with clip-to-edge (k_final_map fallback)
__device__ __forceinline__ void bicubic3_gen(const float* __restrict__ Ib, double xg, double yg, float Iw[3]) {
    double fx = floor(xg), fy = floor(yg);
    int xi = (int)fx, yi = (int)fy;
    float tx = (float)(xg - fx), ty = (float)(yg - fy);
    float wx[4], wyv[4];
    int xx[4], yy[4];
#pragma unroll
    for (int k = 0; k < 4; k++) {
        wx[k] = cubicw(tx - (float)(k - 1)); wyv[k] = cubicw(ty - (float)(k - 1));
        xx[k] = min(max(xi + k - 1, 0), WW - 1);
        yy[k] = min(max(yi + k - 1, 0), HH - 1);
    }
    Iw[0] = 0.f; Iw[1] = 0.f; Iw[2] = 0.f;
#pragma unroll
    for (int j = 0; j < 4; j++) {
        const float* row = Ib + yy[j] * (WW * 3);
        float r0 = 0.f, r1 = 0.f, r2 = 0.f;
#pragma unroll
        for (int k = 0; k < 4; k++) {
            const float* q = row + xx[k] * 3;
            r0 = fmaf(wx[k], q[0], r0); r1 = fmaf(wx[k], q[1], r1); r2 = fmaf(wx[k], q[2], r2);
        }
        Iw[0] = fmaf(wyv[j], r0, Iw[0]);
        Iw[1] = fmaf(wyv[j], r1, Iw[1]);
        Iw[2] = fmaf(wyv[j], r2, Iw[2]);
    }
}

// LDS bicubic from float4-padded staged tile (identical fma order)
__device__ __forceinline__ void bicubic3_lds(const lf4* __restrict__ T, int ssx, int ssy,
                                             float tx, float ty, float Iw[3]) {
    float wx[4], wyv[4];
#pragma unroll
    for (int k = 0; k < 4; k++) { wx[k] = cubicw(tx - (float)(k - 1)); wyv[k] = cubicw(ty - (float)(k - 1)); }
    Iw[0] = 0.f; Iw[1] = 0.f; Iw[2] = 0.f;
    const lf4* bp = T + (ssy - 1) * PITCH2 + (ssx - 1);
#pragma unroll
    for (int j = 0; j < 4; j++) {
        lf4 t0 = bp[j * PITCH2 + 0], t1 = bp[j * PITCH2 + 1], t2 = bp[j * PITCH2 + 2], t3 = bp[j * PITCH2 + 3];
        float r0 = fmaf(wx[0], t0.x, 0.f); r0 = fmaf(wx[1], t1.x, r0); r0 = fmaf(wx[2], t2.x, r0); r0 = fmaf(wx[3], t3.x, r0);
        float r1 = fmaf(wx[0], t0.y, 0.f); r1 = fmaf(wx[1], t1.y, r1); r1 = fmaf(wx[2], t2.y, r1); r1 = fmaf(wx[3], t3.y, r1);
        float r2 = fmaf(wx[0], t0.z, 0.f); r2 = fmaf(wx[1], t1.z, r2); r2 = fmaf(wx[2], t2.z, r2); r2 = fmaf(wx[3], t3.z, r2);
        Iw[0] = fmaf(wyv[j], r0, Iw[0]);
        Iw[1] = fmaf(wyv[j], r1, Iw[1]);
        Iw[2] = fmaf(wyv[j], r2, Iw[2]);
    }
}

// Registers-only 6x6 SPD solve + affine compose. Fully unrolled Cholesky.
__device__ __forceinline__
void solve6_fast(const double* __restrict__ Sb, const double* __restrict__ pc,
                 double pn[6], int* convp) {
    const double b0 = Sb[0], b1 = Sb[3], b2 = Sb[1], b3 = Sb[2], b4 = Sb[4], b5 = Sb[5];
    const double h00 = Sb[6]  + 1e-6, h01 = Sb[12], h02 = Sb[7],  h03 = Sb[8],  h04 = Sb[13], h05 = Sb[14];
    const double h11 = Sb[18] + 1e-6, h12 = Sb[13], h13 = Sb[14], h14 = Sb[19], h15 = Sb[20];
    const double h22 = Sb[9]  + 1e-6, h23 = Sb[10], h24 = Sb[15], h25 = Sb[16];
    const double h33 = Sb[11] + 1e-6, h34 = Sb[16], h35 = Sb[17];
    const double h44 = Sb[21] + 1e-6, h45 = Sb[22];
    const double h55 = Sb[23] + 1e-6;

    const double l00 = sqrt(h00);
    const double i0 = 1.0 / l00;
    const double l10 = h01 * i0, l20 = h02 * i0, l30 = h03 * i0, l40 = h04 * i0, l50 = h05 * i0;
    const double l11 = sqrt(h11 - l10 * l10);
    const double i1 = 1.0 / l11;
    const double l21 = (h12 - l20 * l10) * i1;
    const double l31 = (h13 - l30 * l10) * i1;
    const double l41 = (h14 - l40 * l10) * i1;
    const double l51 = (h15 - l50 * l10) * i1;
    const double l22 = sqrt(h22 - l20 * l20 - l21 * l21);
    const double i2 = 1.0 / l22;
    const double l32 = (h23 - l30 * l20 - l31 * l21) * i2;
    const double l42 = (h24 - l40 * l20 - l41 * l21) * i2;
    const double l52 = (h25 - l50 * l20 - l51 * l21) * i2;
    const double l33 = sqrt(h33 - l30 * l30 - l31 * l31 - l32 * l32);
    const double i3 = 1.0 / l33;
    const double l43 = (h34 - l40 * l30 - l41 * l31 - l42 * l32) * i3;
    const double l53 = (h35 - l50 * l30 - l51 * l31 - l52 * l32) * i3;
    const double l44 = sqrt(h44 - l40 * l40 - l41 * l41 - l42 * l42 - l43 * l43);
    const double i4 = 1.0 / l44;
    const double l54 = (h45 - l50 * l40 - l51 * l41 - l52 * l42 - l53 * l43) * i4;
    const double l55 = sqrt(h55 - l50 * l50 - l51 * l51 - l52 * l52 - l53 * l53 - l54 * l54);
    const double i5 = 1.0 / l55;

    const double y0 = b0 * i0;
    const double y1 = (b1 - l10 * y0) * i1;
    const double y2 = (b2 - l20 * y0 - l21 * y1) * i2;
    const double y3 = (b3 - l30 * y0 - l31 * y1 - l32 * y2) * i3;
    const double y4 = (b4 - l40 * y0 - l41 * y1 - l42 * y2 - l43 * y3) * i4;
    const double y5 = (b5 - l50 * y0 - l51 * y1 - l52 * y2 - l53 * y3 - l54 * y4) * i5;

    const double d5 = y5 * i5;
    const double d4 = (y4 - l54 * d5) * i4;
    const double d3 = (y3 - l43 * d4 - l53 * d5) * i3;
    const double d2 = (y2 - l32 * d3 - l42 * d4 - l52 * d5) * i2;
    const double d1 = (y1 - l21 * d2 - l31 * d3 - l41 * d4 - l51 * d5) * i1;
    const double d0 = (y0 - l10 * d1 - l20 * d2 - l30 * d3 - l40 * d4 - l50 * d5) * i0;

    const double nrm = sqrt(d0*d0 + d1*d1 + d2*d2 + d3*d3 + d4*d4 + d5*d5);
    *convp = (nrm < 1e-3) ? 1 : 0;

    const double m00 = 1.0 + pc[2], m01 = pc[3], m02 = pc[0];
    const double m10 = pc[4], m11 = 1.0 + pc[5], m12 = pc[1];
    const double q00 = 1.0 + d2, q01 = d3, q02 = d0;
    const double q10 = d4, q11 = 1.0 + d5, q12 = d1;
    const double det = q00 * q11 - q01 * q10;
    const double j00 = q11 / det, j01 = -q01 / det;
    const double j10 = -q10 / det, j11 = q00 / det;
    const double jt0 = -(j00 * q02 + j01 * q12);
    const double jt1 = -(j10 * q02 + j11 * q12);
    const double n00 = m00 * j00 + m01 * j10;
    const double n01 = m00 * j01 + m01 * j11;
    const double n02 = m00 * jt0 + m01 * jt1 + m02;
    const double n10 = m10 * j00 + m11 * j10;
    const double n11 = m10 * j01 + m11 * j11;
    const double n12 = m10 * jt0 + m11 * jt1 + m12;
    pn[0] = n02;
    pn[1] = n12;
    pn[2] = n00 - 1.0;
    pn[3] = n01;
    pn[4] = n10;
    pn[5] = n11 - 1.0;
}

extern "C" __global__ __launch_bounds__(256)
void k_init(const float* __restrict__ p0, double* __restrict__ p_store,
            int* __restrict__ done0, double* __restrict__ S_part_all,
            double* __restrict__ Sf_part) {
    const int idx = blockIdx.x * 256 + threadIdx.x;
    const int n = MAXIT * KB_ * BB * SPS;          // 24576 doubles
    for (int i = idx; i < n; i += gridDim.x * 256) S_part_all[i] = 0.0;
    if (blockIdx.x == 0) {
        const int tid = threadIdx.x;
        if (tid < KB_ * BB * 4) Sf_part[tid] = 0.0;      // 256 doubles
        if (tid < BB * NPAR) p_store[tid] = (double)p0[tid];
        if (tid < BB) done0[tid] = 0;
    }
}

// 4-row x 128-col tile; wave w owns row y0+w, lane owns 2 CONSECUTIVE px
// (shared I1 stencil loads: 7 vf4 per pair vs 10). I2 LDS-staged with
// compile-time width 140 (runtime-width div was ~20 VALU instrs/element).
// Bucketed line-padded atomics (R13: contention fix, -87 us).
extern "C" __global__ __launch_bounds__(256)
void k_iter(const float* __restrict__ I1, const float* __restrict__ I2,
            const double* __restrict__ p_in, const int* __restrict__ done_in,
            const double* __restrict__ S_in, double* __restrict__ S_out,
            double* __restrict__ p_out_g, int* __restrict__ done_out_g,
            int first) {
    __shared__ lf4 SMEM[NR2 * PITCH2];      // 18048 B; aliased as reduction scratch
    __shared__ double Ssum[NACC];
    __shared__ double pbc[NPAR];
    __shared__ int dbc;
    const int tid = threadIdx.x;
    const int b = blockIdx.y;

    if (!first) {
        if (tid < NACC) {
            double a0 = 0.0, a1 = 0.0;
#pragma unroll
            for (int k = 0; k < KB_; k += 2) {
                a0 += S_in[((size_t)(k * BB + b)) * SPS + tid];
                a1 += S_in[((size_t)((k + 1) * BB + b)) * SPS + tid];
            }
            Ssum[tid] = a0 + a1;
        }
        __syncthreads();
    }
    if (tid == 0) {
        if (first) {
#pragma unroll
            for (int i = 0; i < NPAR; i++) pbc[i] = p_in[b * NPAR + i];
            dbc = done_in[b];
        } else {
            if (done_in[b]) {
#pragma unroll
                for (int i = 0; i < NPAR; i++) pbc[i] = p_in[b * NPAR + i];
                dbc = 1;
            } else {
                double pn[6]; int conv;
                solve6_fast(Ssum, p_in + b * NPAR, pn, &conv);
#pragma unroll
                for (int i = 0; i < NPAR; i++) pbc[i] = pn[i];
                dbc = conv;
            }
            if (blockIdx.x == 0) {
#pragma unroll
                for (int i = 0; i < NPAR; i++) p_out_g[b * NPAR + i] = pbc[i];
                done_out_g[b] = dbc;
            }
        }
    }
    __syncthreads();
    if (dbc) return;                        // frozen batch: S_out stays zero

    const int tix = blockIdx.x;             // 0..272
    const int rt = tix / 3, win = tix - rt * 3;
    const int y0 = 10 + rt * 4;             // rows y0..y0+3, all in [10,373]
    const int x0 = 10 + win * 128;
    const int W = (win == 2) ? 108 : 128;
    const int sx0 = x0 - 6;

    const double M00 = 1.0 + pbc[2], M01 = pbc[3], M02 = pbc[0];
    const double M10 = pbc[4], M11 = 1.0 + pbc[5], M12 = pbc[1];
    const float* I1b = I1 + (size_t)b * HWPIX * 3;
    const float* I2b = I2 + (size_t)b * HWPIX * 3;

    const double ygc = M10 * (double)(x0 + 64) + M11 * ((double)y0 + 1.5) + M12;
    const int r0 = (int)fmin(fmax(floor(ygc) - 3.0, -100000.0), 100000.0);

    // stage I2 rows r0..r0+7 (clamped) — one dwordx4 per element, const width
    for (int i = tid; i < NR2 * WS2C; i += 256) {
        const int r = i / WS2C, c = i - r * WS2C;     // compile-time divisor
        const int gr = min(max(r0 + r, 0), HH - 1);
        const int gc = min(sx0 + c, WW - 1);           // sx0 >= 4
        SMEM[r * PITCH2 + c] = ldpx3(I2b, gr * WW + gc);
    }
    __syncthreads();

    const int wid = tid >> 6, lane = tid & 63;
    const int y = y0 + wid;                 // wave-uniform row, <= 373
    const double Y = (double)y;
    const double Bx = M01 * Y + M02;
    const double By = M11 * Y + M12;

    double s[13];
#pragma unroll
    for (int i = 0; i < 13; i++) s[i] = 0.0;
    // s: 0=T0 1=T0X 2=T1 3=T1X 4=A 5=AX 6=AXX 7=B 8=BX 9=BXX 10=C 11=CX 12=CXX

    // pair I1 loads (clamped base keeps masked lanes memory-safe)
    const int colb = 2 * lane;              // 0..126
    const int x1 = x0 + colb;
    const int x1c = min(x1, WW - DEL - 2);  // <=372; stencil span x1c-1..x1c+3 in-bounds
    const float* cb = I1b + (y * WW + x1c) * 3;
    const vf4 Ar = ldv4(cb - 3);            // f-3..f
    const vf4 Br = ldv4(cb + 1);            // f+1..f+4
    const vf4 Cr = ldv4(cb + 5);            // f+5..f+8
    const vf4 Ur = ldv4(cb - WW * 3);       // up row f..f+3
    const vf4 U2r = ldv4(cb - WW * 3 + 2);  // up row f+2..f+5
    const vf4 Dr = ldv4(cb + WW * 3);
    const vf4 D2r = ldv4(cb + WW * 3 + 2);

#pragma unroll
    for (int j = 0; j < 2; j++) {
        const int col = colb + j;
        const int x = x0 + col;
        const double X = (double)x;
        const double xg = fma(M00, X, Bx);
        const double yg = fma(M10, X, By);
        const double gx = rint(xg), gy = rint(yg);   // half-to-even like jnp.round
        const bool ok = (col < W) &&
                        (gx >= (double)DEL && gx <= (double)(WW - DEL) &&
                         gy >= (double)DEL && gy <= (double)(HH - DEL));
        const double fx = floor(xg), fy = floor(yg);
        const int xi = (int)fx, yi = (int)fy;
        const float tx = (float)(xg - fx), ty = (float)(yg - fy);
        const int sxi = xi - sx0, syi = yi - r0;
        const bool inwin = ok && (sxi >= 1) && (sxi <= WS2C - 3) && (syi >= 1) && (syi <= NR2 - 3);

        float Iw[3];
        if (ok && !inwin) {
            bicubic3_fast(I2b, xg, yg, Iw);   // rare drift fallback
        } else {
            const int ssx = inwin ? sxi : 8;
            const int ssy = inwin ? syi : 2;
            bicubic3_lds(SMEM, ssx, ssy, tx, ty, Iw);
        }

        float cl[3], cv[3], cr[3], cu[3], cd[3];
        if (j == 0) {
            cl[0] = Ar.x; cl[1] = Ar.y; cl[2] = Ar.z;
            cv[0] = Ar.w; cv[1] = Br.x; cv[2] = Br.y;
            cr[0] = Br.z; cr[1] = Br.w; cr[2] = Cr.x;
            cu[0] = Ur.x; cu[1] = Ur.y; cu[2] = Ur.z;
            cd[0] = Dr.x; cd[1] = Dr.y; cd[2] = Dr.z;
        } else {
            cl[0] = Ar.w; cl[1] = Br.x; cl[2] = Br.y;
            cv[0] = Br.z; cv[1] = Br.w; cv[2] = Cr.x;
            cr[0] = Cr.y; cr[1] = Cr.z; cr[2] = Cr.w;
            cu[0] = Ur.w; cu[1] = U2r.z; cu[2] = U2r.w;
            cd[0] = Dr.w; cd[1] = D2r.z; cd[2] = D2r.w;
        }

        const float msk = ok ? 1.0f : 0.0f;
        float Af = 0.f, Bf = 0.f, Cf = 0.f, T0f = 0.f, T1f = 0.f;
#pragma unroll
        for (int ch = 0; ch < 3; ch++) {
            const float Ix = (cr[ch] - cl[ch]) * 0.5f;
            const float Iy = (cd[ch] - cu[ch]) * 0.5f;
            const float d = Iw[ch] - cv[ch];
            const float u = d * 20.0f;
            const float w = msk / sqrtf(fmaf(u, u, 1.0f));
            const float wd = w * d;
            T0f = fmaf(Ix, wd, T0f);
            T1f = fmaf(Iy, wd, T1f);
            const float wIx = w * Ix;
            Af = fmaf(wIx, Ix, Af);
            Bf = fmaf(wIx, Iy, Bf);
            Cf = fmaf(w * Iy, Iy, Cf);
        }
        const double T0 = (double)T0f, T1 = (double)T1f;
        const double A = (double)Af, Bd = (double)Bf, Cd = (double)Cf;
        const double XX = X * X;
        s[0] += T0;  s[1] = fma(T0, X, s[1]);
        s[2] += T1;  s[3] = fma(T1, X, s[3]);
        s[4] += A;   s[5] = fma(A, X, s[5]);   s[6] = fma(A, XX, s[6]);
        s[7] += Bd;  s[8] = fma(Bd, X, s[8]);  s[9] = fma(Bd, XX, s[9]);
        s[10] += Cd; s[11] = fma(Cd, X, s[11]); s[12] = fma(Cd, XX, s[12]);
    }

    // one shuffle fold (lane+32), then lanes 0..31 dump raw partials to LDS
#pragma unroll
    for (int i = 0; i < 13; i++) s[i] += __shfl_down(s[i], 32, 64);

    __syncthreads();                         // staged reads done; alias as scratch
    double* scr = (double*)SMEM;             // 4 waves x 32 lanes x 13 f64 = 13312 B
    if (lane < 32) {
        double* o = scr + ((size_t)(wid * 32 + lane)) * 13;
#pragma unroll
        for (int i = 0; i < 13; i++) o[i] = s[i];
    }
    __syncthreads();

    if (tid < NACC) {
        // component -> (s index, Y power)
        const int comp[NACC] = {0,1,0, 2,3,2, 4,5,4, 6,5,4, 7,8,7, 9,8,7, 10,11,10, 12,11,10};
        const int ypw[NACC]  = {0,0,1, 0,0,1, 0,0,1, 0,1,2, 0,0,1, 0,1,2, 0,0,1,   0,1,2};
        const int cix = comp[tid], pw = ypw[tid];
        double acc = 0.0;
        for (int w = 0; w < 4; w++) {
            const double* basep = scr + ((size_t)(w * 32)) * 13 + cix;
            double part = 0.0;
            for (int l = 0; l < 32; l++) part += basep[(size_t)l * 13];
            const double Yw = (double)(y0 + w);
            const double f = (pw == 0) ? 1.0 : ((pw == 1) ? Yw : Yw * Yw);
            acc = fma(f, part, acc);
        }
        const int bkt = blockIdx.x & (KB_ - 1);
        unsafeAtomicAdd(&S_out[((size_t)(bkt * BB + b)) * SPS + tid], acc);
    }
}

// 4-row x 128-col tiles over the FULL image; lane owns 2 consecutive px.
// Vectorized pair stores (dwordx4+dwordx2 per array). Prologue computes pf.
extern "C" __global__ __launch_bounds__(256)
void k_final_map(const float* __restrict__ I1, const float* __restrict__ I2,
                 const double* __restrict__ p_in, const int* __restrict__ done_in,
                 const double* __restrict__ S_in, double* __restrict__ pf_g,
                 float* __restrict__ DI_out, float* __restrict__ Iw_out,
                 double* __restrict__ Sf_part) {
    __shared__ lf4 I2S[NR2 * PITCH2];
    __shared__ double wsum[4][2];
    __shared__ double Ssum[NACC];
    __shared__ double pbc[NPAR];
    const int tid = threadIdx.x;
    const int b = blockIdx.y;

    if (tid < NACC) {
        double a0 = 0.0, a1 = 0.0;
#pragma unroll
        for (int k = 0; k < KB_; k += 2) {
            a0 += S_in[((size_t)(k * BB + b)) * SPS + tid];
            a1 += S_in[((size_t)((k + 1) * BB + b)) * SPS + tid];
        }
        Ssum[tid] = a0 + a1;
    }
    __syncthreads();
    if (tid == 0) {
        if (done_in[b]) {
#pragma unroll
            for (int i = 0; i < NPAR; i++) pbc[i] = p_in[b * NPAR + i];
        } else {
            double pn[6]; int conv;
            solve6_fast(Ssum, p_in + b * NPAR, pn, &conv);
#pragma unroll
            for (int i = 0; i < NPAR; i++) pbc[i] = pn[i];
        }
        if (blockIdx.x == 0) {
#pragma unroll
            for (int i = 0; i < NPAR; i++) pf_g[b * NPAR + i] = pbc[i];
        }
    }
    __syncthreads();

    const int tix = blockIdx.x;                 // 0..287
    const int rt = tix / 3, win = tix - rt * 3;
    const int y0 = rt * 4;
    const int x0 = win * 128;
    const int sx0 = x0 - 6;

    const double M00 = 1.0 + pbc[2], M01 = pbc[3], M02 = pbc[0];
    const double M10 = pbc[4], M11 = 1.0 + pbc[5], M12 = pbc[1];
    const float* I1b = I1 + (size_t)b * HWPIX * 3;
    const float* I2b = I2 + (size_t)b * HWPIX * 3;
    float* DIb = DI_out + (size_t)b * HWPIX * 3;
    float* Iwb = Iw_out + (size_t)b * HWPIX * 3;

    const double ygc = M10 * (double)(x0 + 64) + M11 * ((double)y0 + 1.5) + M12;
    const int r0 = (int)fmin(fmax(floor(ygc) - 3.0, -100000.0), 100000.0);

    for (int i = tid; i < NR2 * WS2C; i += 256) {
        const int r = i / WS2C, c = i - r * WS2C;
        const int gr = min(max(r0 + r, 0), HH - 1);    // clamped staging == clip-to-edge
        const int gc = min(max(sx0 + c, 0), WW - 1);
        I2S[r * PITCH2 + c] = ldpx3(I2b, gr * WW + gc);
    }
    __syncthreads();

    const int row = tid >> 6, lane = tid & 63;
    const int y = y0 + row;
    const int x1 = x0 + 2 * lane;               // even, 0..382
    const int pix1 = y * WW + x1;

    float Iwp[2][3];
    bool mp[2];
    double rho_s = 0.0, cnt_s = 0.0;

    // pair I1 center load (always in-bounds: last pair ends exactly at image end)
    const float* cbase = I1b + (size_t)pix1 * 3;
    const vf4 Ac = ldv4(cbase);                 // f..f+3
    const vf4 A2c = ldv4(cbase + 2);            // f+2..f+5

#pragma unroll
    for (int j = 0; j < 2; j++) {
        const int x = x1 + j;
        const double X = (double)x, Yd = (double)y;
        const double xg = fma(M00, X, fma(M01, Yd, M02));
        const double yg = fma(M10, X, fma(M11, Yd, M12));
        const double fx = floor(xg), fy = floor(yg);
        const int xi = (int)fx, yi = (int)fy;
        const float tx = (float)(xg - fx), ty = (float)(yg - fy);
        const int sxi = xi - sx0, syi = yi - r0;
        const bool inwin = (sxi >= 1) && (sxi <= WS2C - 3) && (syi >= 1) && (syi <= NR2 - 3);

        if (inwin) bicubic3_lds(I2S, sxi, syi, tx, ty, Iwp[j]);
        else       bicubic3_gen(I2b, xg, yg, Iwp[j]);

        const bool v1 = (x >= DEL) && (x < WW - DEL) && (y >= DEL) && (y < HH - DEL);
        const double gx = rint(xg), gy = rint(yg);
        const bool wm = (gx >= (double)DEL && gx <= (double)(WW - DEL) &&
                         gy >= (double)DEL && gy <= (double)(HH - DEL));
        mp[j] = v1 && wm;
    }

    // vectorized Iw store (pair = 6 floats)
    {
        float* wp = Iwb + (size_t)pix1 * 3;
        *(uvf4*)wp = (vf4){Iwp[0][0], Iwp[0][1], Iwp[0][2], Iwp[1][0]};
        *(f2v*)(wp + 4) = (f2v){Iwp[1][1], Iwp[1][2]};
    }
    // DI pair + rho
    {
        const float cv1[3] = {Ac.x, Ac.y, Ac.z};
        const float cv2[3] = {Ac.w, A2c.z, A2c.w};
        float dv[6];
#pragma unroll
        for (int ch = 0; ch < 3; ch++) {
            const float d1 = mp[0] ? (Iwp[0][ch] - cv1[ch]) : 0.0f;
            const float d2 = mp[1] ? (Iwp[1][ch] - cv2[ch]) : 0.0f;
            dv[ch] = d1;
            dv[3 + ch] = d2;
            if (mp[0]) {
                const float u = d1 * 20.0f;
                rho_s += (double)(0.005f * (sqrtf(fmaf(u, u, 1.0f)) - 1.0f));
            }
            if (mp[1]) {
                const float u = d2 * 20.0f;
                rho_s += (double)(0.005f * (sqrtf(fmaf(u, u, 1.0f)) - 1.0f));
            }
        }
        if (mp[0]) cnt_s += 3.0;
        if (mp[1]) cnt_s += 3.0;
        float* dp_ = DIb + (size_t)pix1 * 3;
        *(uvf4*)dp_ = (vf4){dv[0], dv[1], dv[2], dv[3]};
        *(f2v*)(dp_ + 4) = (f2v){dv[4], dv[5]};
    }

#pragma unroll
    for (int off = 32; off >= 1; off >>= 1) {
        rho_s += __shfl_down(rho_s, off, 64);
        cnt_s += __shfl_down(cnt_s, off, 64);
    }
    if (lane == 0) { wsum[row][0] = rho_s; wsum[row][1] = cnt_s; }
    __syncthreads();
    if (tid < 2) {
        double sv = wsum[0][tid] + wsum[1][tid] + wsum[2][tid] + wsum[3][tid];
        const int bkt = blockIdx.x & (KB_ - 1);
        unsafeAtomicAdd(&Sf_part[((size_t)(bkt * BB + b)) * 4 + tid], sv);
    }
}

extern "C" __global__ void k_finish(const double* __restrict__ p_fin,
                                    const double* __restrict__ Sf_part,
                                    float* __restrict__ out) {
    const int tid = threadIdx.x;  // 64 threads
    if (tid < BB * NPAR) out[tid] = (float)p_fin[tid];           // pf
    if (tid >= 48 && tid < 48 + BB) {
        const int b = tid - 48;
        double rs = 0.0, cs = 0.0;
#pragma unroll
        for (int k = 0; k < KB_; k++) {
            rs += Sf_part[((size_t)(k * BB + b)) * 4 + 0];
            cs += Sf_part[((size_t)(k * BB + b)) * 4 + 1];
        }
        out[48 + b] = (float)(rs / fmax(cs, 1.0));               // err
    }
}

extern "C" void kernel_launch(void* const* d_in, const int* in_sizes, int n_in,
                              void* d_out, int out_size, void* d_ws, size_t ws_size,
                              hipStream_t stream) {
    const float* I1 = (const float*)d_in[0];
    const float* I2 = (const float*)d_in[1];
    const float* p0 = (const float*)d_in[2];
    float* out = (float*)d_out;

    // ws layout (8B-aligned):
    // [0)      p_store    (MAXIT+1)*48 doubles = 4992 B   (p[it]; p[12]=pf)
    // [4992)   done       (MAXIT+1)*8 ints     = 416 B
    // [5408)   S_part_all MAXIT*8*8*32 doubles = 196608 B (bucketed, line-padded)
    // [202016) Sf_part    8*8*4 doubles        = 2048 B
    double* p_store = (double*)d_ws;
    int* done_flags = (int*)((char*)d_ws + 4992);
    double* S_part_all = (double*)((char*)d_ws + 5408);
    double* Sf_part = (double*)((char*)d_ws + 202016);

    k_init<<<8, 256, 0, stream>>>(p0, p_store, done_flags, S_part_all, Sf_part);

    const size_t SIT = (size_t)KB_ * BB * SPS;   // doubles per iteration
    dim3 gridI(NRT4 * 3, BB), blkI(256);
    for (int it = 0; it < MAXIT; it++) {
        const int first = (it == 0) ? 1 : 0;
        const double* p_in = p_store + (size_t)(first ? 0 : (it - 1)) * BB * NPAR;
        const int* d_in_f = done_flags + (first ? 0 : (it - 1)) * BB;
        const double* S_in = S_part_all + (size_t)(first ? 0 : (it - 1)) * SIT; // unused if first
        k_iter<<<gridI, blkI, 0, stream>>>(I1, I2, p_in, d_in_f, S_in,
                                           S_part_all + (size_t)it * SIT,
                                           p_store + (size_t)it * BB * NPAR,
                                           done_flags + it * BB, first);
    }
    // k_iter(11) wrote p(11)/done(11); k_final_map computes p(12)=pf from buckets of it=11.
    float* DI_out = out + 56;
    float* Iw_out = out + 56 + (size_t)BB * HWPIX * 3;
    dim3 gridF(96 * 3, BB), blkF(256);
    k_final_map<<<gridF, blkF, 0, stream>>>(I1, I2,
                                            p_store + (size_t)11 * BB * NPAR,
                                            done_flags + 11 * BB,
                                            S_part_all + (size_t)11 * SIT,
                                            p_store + (size_t)MAXIT * BB * NPAR,
                                            DI_out, Iw_out, Sf_part);
    k_finish<<<1, 64, 0, stream>>>(p_store + (size_t)MAXIT * BB * NPAR, Sf_part, out);
}

// Round 15
// 435.909 us; speedup vs baseline: 1.0479x; 1.0479x over previous
//
#include <hip/hip_runtime.h>
#include <math.h>

#define BB 8
#define HH 384
#define WW 384
#define NPAR 6
#define DEL 10
#define MAXIT 12
#define NACC 24
#define HWPIX (HH*WW)
#define NRT4 91                 // 4-row tiles covering rows 10..373 exactly
#define PITCH2 141              // staged I2 cols (140 used)
#define NR2 8                   // staged I2 rows
#define WS2C 140                // compile-time staging width (div -> magic mul)
#define KB_ 8                   // atomic buckets (blockIdx.x & 7)
#define SPS 32                  // doubles per (bucket,b) slot (256 B, line-padded)

typedef float vf4 __attribute__((ext_vector_type(4)));
typedef vf4 uvf4 __attribute__((aligned(4)));      // 4B-aligned global dwordx4
typedef float f2v __attribute__((ext_vector_type(2), aligned(4)));
typedef float lf4 __attribute__((ext_vector_type(4)));  // 16B-aligned (LDS)

__device__ __forceinline__ vf4 ldv4(const float* p) { return *(const uvf4*)p; }

// One-instruction staged-pixel load: dwordx4 covering this pixel's 3 floats.
// Tail guard: last pixel uses a shifted load to avoid a 4B OOB read.
__device__ __forceinline__ lf4 ldpx3(const float* __restrict__ Ib, int pixoff) {
    const int fo = pixoff * 3;
    if (fo + 4 <= HWPIX * 3) {
        vf4 v = ldv4(Ib + fo);
        return (lf4){v.x, v.y, v.z, 0.f};
    }
    vf4 v = ldv4(Ib + fo - 1);
    return (lf4){v.y, v.z, v.w, 0.f};
}

__device__ __forceinline__ float cubicw(float s) {
    s = fabsf(s);
    float s2 = s * s, s3 = s2 * s;
    float w1 = 1.5f * s3 - 2.5f * s2 + 1.0f;
    float w2 = -0.5f * s3 + 2.5f * s2 - 4.0f * s + 2.0f;
    return (s <= 1.0f) ? w1 : ((s < 2.0f) ? w2 : 0.0f);
}

// global fast-path bicubic (taps guaranteed in-bounds; drift fallback in k_iter)
__device__ __forceinline__ void bicubic3_fast(const float* __restrict__ Ib, double xg, double yg, float Iw[3]) {
    double fx = floor(xg), fy = floor(yg);
    float tx = (float)(xg - fx), ty = (float)(yg - fy);
    int xi = (int)fx, yi = (int)fy;
    float wx[4], wyv[4];
#pragma unroll
    for (int k = 0; k < 4; k++) { wx[k] = cubicw(tx - (float)(k - 1)); wyv[k] = cubicw(ty - (float)(k - 1)); }
    Iw[0] = 0.f; Iw[1] = 0.f; Iw[2] = 0.f;
    const float* base = Ib + (yi - 1) * (WW * 3) + (xi - 1) * 3;
#pragma unroll
    for (int j = 0; j < 4; j++) {
        const float* r = base + j * (WW * 3);
        vf4 v0 = ldv4(r), v1 = ldv4(r + 4), v2 = ldv4(r + 8);
        float r0 = fmaf(wx[0], v0.x, 0.f); r0 = fmaf(wx[1], v0.w, r0); r0 = fmaf(wx[2], v1.z, r0); r0 = fmaf(wx[3], v2.y, r0);
        float r1 = fmaf(wx[0], v0.y, 0.f); r1 = fmaf(wx[1], v1.x, r1); r1 = fmaf(wx[2], v1.w, r1); r1 = fmaf(wx[3], v2.z, r1);
        float r2 = fmaf(wx[0], v0.z, 0.f); r2 = fmaf(wx[1], v1.y, r2); r2 = fmaf(wx[2], v2.x, r2); r2 = fmaf(wx[3], v2.w, r2);
        Iw[0] = fmaf(wyv[j], r0, Iw[0]);
        Iw[1] = fmaf(wyv[j], r1, Iw[1]);
        Iw[2] = fmaf(wyv[j], r2, Iw[2]);
    }
}

// general bicubic with clip-to-edge (k_final_map fallback)
__device__ __forceinline__ void bicubic3_gen(const float* __restrict__ Ib, double xg, double yg, float Iw[3]) {
    double fx = floor(xg), fy = floor(yg);
    int xi = (int)fx, yi = (int)fy;
    float tx = (float)(xg - fx), ty = (float)(yg - fy);
    float wx[4], wyv[4];
    int xx[4], yy[4];
#pragma unroll
    for (int k = 0; k < 4; k++) {
        wx[k] = cubicw(tx - (float)(k - 1)); wyv[k] = cubicw(ty - (float)(k - 1));
        xx[k] = min(max(xi + k - 1, 0), WW - 1);
        yy[k] = min(max(yi + k - 1, 0), HH - 1);
    }
    Iw[0] = 0.f; Iw[1] = 0.f; Iw[2] = 0.f;
#pragma unroll
    for (int j = 0; j < 4; j++) {
        const float* row = Ib + yy[j] * (WW * 3);
        float r0 = 0.f, r1 = 0.f, r2 = 0.f;
#pragma unroll
        for (int k = 0; k < 4; k++) {
            const float* q = row + xx[k] * 3;
            r0 = fmaf(wx[k], q[0], r0); r1 = fmaf(wx[k], q[1], r1); r2 = fmaf(wx[k], q[2], r2);
        }
        Iw[0] = fmaf(wyv[j], r0, Iw[0]);
        Iw[1] = fmaf(wyv[j], r1, Iw[1]);
        Iw[2] = fmaf(wyv[j], r2, Iw[2]);
    }
}

// LDS bicubic from float4-padded staged tile (identical fma order)
__device__ __forceinline__ void bicubic3_lds(const lf4* __restrict__ T, int ssx, int ssy,
                                             float tx, float ty, float Iw[3]) {
    float wx[4], wyv[4];
#pragma unroll
    for (int k = 0; k < 4; k++) { wx[k] = cubicw(tx - (float)(k - 1)); wyv[k] = cubicw(ty - (float)(k - 1)); }
    Iw[0] = 0.f; Iw[1] = 0.f; Iw[2] = 0.f;
    const lf4* bp = T + (ssy - 1) * PITCH2 + (ssx - 1);
#pragma unroll
    for (int j = 0; j < 4; j++) {
        lf4 t0 = bp[j * PITCH2 + 0], t1 = bp[j * PITCH2 + 1], t2 = bp[j * PITCH2 + 2], t3 = bp[j * PITCH2 + 3];
        float r0 = fmaf(wx[0], t0.x, 0.f); r0 = fmaf(wx[1], t1.x, r0); r0 = fmaf(wx[2], t2.x, r0); r0 = fmaf(wx[3], t3.x, r0);
        float r1 = fmaf(wx[0], t0.y, 0.f); r1 = fmaf(wx[1], t1.y, r1); r1 = fmaf(wx[2], t2.y, r1); r1 = fmaf(wx[3], t3.y, r1);
        float r2 = fmaf(wx[0], t0.z, 0.f); r2 = fmaf(wx[1], t1.z, r2); r2 = fmaf(wx[2], t2.z, r2); r2 = fmaf(wx[3], t3.z, r2);
        Iw[0] = fmaf(wyv[j], r0, Iw[0]);
        Iw[1] = fmaf(wyv[j], r1, Iw[1]);
        Iw[2] = fmaf(wyv[j], r2, Iw[2]);
    }
}

// Registers-only 6x6 SPD solve + affine compose. Fully unrolled Cholesky.
__device__ __forceinline__
void solve6_fast(const double* __restrict__ Sb, const double* __restrict__ pc,
                 double pn[6], int* convp) {
    const double b0 = Sb[0], b1 = Sb[3], b2 = Sb[1], b3 = Sb[2], b4 = Sb[4], b5 = Sb[5];
    const double h00 = Sb[6]  + 1e-6, h01 = Sb[12], h02 = Sb[7],  h03 = Sb[8],  h04 = Sb[13], h05 = Sb[14];
    const double h11 = Sb[18] + 1e-6, h12 = Sb[13], h13 = Sb[14], h14 = Sb[19], h15 = Sb[20];
    const double h22 = Sb[9]  + 1e-6, h23 = Sb[10], h24 = Sb[15], h25 = Sb[16];
    const double h33 = Sb[11] + 1e-6, h34 = Sb[16], h35 = Sb[17];
    const double h44 = Sb[21] + 1e-6, h45 = Sb[22];
    const double h55 = Sb[23] + 1e-6;

    const double l00 = sqrt(h00);
    const double i0 = 1.0 / l00;
    const double l10 = h01 * i0, l20 = h02 * i0, l30 = h03 * i0, l40 = h04 * i0, l50 = h05 * i0;
    const double l11 = sqrt(h11 - l10 * l10);
    const double i1 = 1.0 / l11;
    const double l21 = (h12 - l20 * l10) * i1;
    const double l31 = (h13 - l30 * l10) * i1;
    const double l41 = (h14 - l40 * l10) * i1;
    const double l51 = (h15 - l50 * l10) * i1;
    const double l22 = sqrt(h22 - l20 * l20 - l21 * l21);
    const double i2 = 1.0 / l22;
    const double l32 = (h23 - l30 * l20 - l31 * l21) * i2;
    const double l42 = (h24 - l40 * l20 - l41 * l21) * i2;
    const double l52 = (h25 - l50 * l20 - l51 * l21) * i2;
    const double l33 = sqrt(h33 - l30 * l30 - l31 * l31 - l32 * l32);
    const double i3 = 1.0 / l33;
    const double l43 = (h34 - l40 * l30 - l41 * l31 - l42 * l32) * i3;
    const double l53 = (h35 - l50 * l30 - l51 * l31 - l52 * l32) * i3;
    const double l44 = sqrt(h44 - l40 * l40 - l41 * l41 - l42 * l42 - l43 * l43);
    const double i4 = 1.0 / l44;
    const double l54 = (h45 - l50 * l40 - l51 * l41 - l52 * l42 - l53 * l43) * i4;
    const double l55 = sqrt(h55 - l50 * l50 - l51 * l51 - l52 * l52 - l53 * l53 - l54 * l54);
    const double i5 = 1.0 / l55;

    const double y0 = b0 * i0;
    const double y1 = (b1 - l10 * y0) * i1;
    const double y2 = (b2 - l20 * y0 - l21 * y1) * i2;
    const double y3 = (b3 - l30 * y0 - l31 * y1 - l32 * y2) * i3;
    const double y4 = (b4 - l40 * y0 - l41 * y1 - l42 * y2 - l43 * y3) * i4;
    const double y5 = (b5 - l50 * y0 - l51 * y1 - l52 * y2 - l53 * y3 - l54 * y4) * i5;

    const double d5 = y5 * i5;
    const double d4 = (y4 - l54 * d5) * i4;
    const double d3 = (y3 - l43 * d4 - l53 * d5) * i3;
    const double d2 = (y2 - l32 * d3 - l42 * d4 - l52 * d5) * i2;
    const double d1 = (y1 - l21 * d2 - l31 * d3 - l41 * d4 - l51 * d5) * i1;
    const double d0 = (y0 - l10 * d1 - l20 * d2 - l30 * d3 - l40 * d4 - l50 * d5) * i0;

    const double nrm = sqrt(d0*d0 + d1*d1 + d2*d2 + d3*d3 + d4*d4 + d5*d5);
    *convp = (nrm < 1e-3) ? 1 : 0;

    const double m00 = 1.0 + pc[2], m01 = pc[3], m02 = pc[0];
    const double m10 = pc[4], m11 = 1.0 + pc[5], m12 = pc[1];
    const double q00 = 1.0 + d2, q01 = d3, q02 = d0;
    const double q10 = d4, q11 = 1.0 + d5, q12 = d1;
    const double det = q00 * q11 - q01 * q10;
    const double j00 = q11 / det, j01 = -q01 / det;
    const double j10 = -q10 / det, j11 = q00 / det;
    const double jt0 = -(j00 * q02 + j01 * q12);
    const double jt1 = -(j10 * q02 + j11 * q12);
    const double n00 = m00 * j00 + m01 * j10;
    const double n01 = m00 * j01 + m01 * j11;
    const double n02 = m00 * jt0 + m01 * jt1 + m02;
    const double n10 = m10 * j00 + m11 * j10;
    const double n11 = m10 * j01 + m11 * j11;
    const double n12 = m10 * jt0 + m11 * jt1 + m12;
    pn[0] = n02;
    pn[1] = n12;
    pn[2] = n00 - 1.0;
    pn[3] = n01;
    pn[4] = n10;
    pn[5] = n11 - 1.0;
}

extern "C" __global__ __launch_bounds__(256)
void k_init(const float* __restrict__ p0, double* __restrict__ p_store,
            int* __restrict__ done0, double* __restrict__ S_part_all,
            double* __restrict__ Sf_part) {
    const int idx = blockIdx.x * 256 + threadIdx.x;
    const int n = MAXIT * KB_ * BB * SPS;          // 24576 doubles
    for (int i = idx; i < n; i += gridDim.x * 256) S_part_all[i] = 0.0;
    if (blockIdx.x == 0) {
        const int tid = threadIdx.x;
        if (tid < KB_ * BB * 4) Sf_part[tid] = 0.0;      // 256 doubles
        if (tid < BB * NPAR) p_store[tid] = (double)p0[tid];
        if (tid < BB) done0[tid] = 0;
    }
}

// R13's exact hot loop (1 px/lane/step, best measured: 439 us total) +
// compile-time staging width (div -> magic mul). Bucketed padded atomics.
extern "C" __global__ __launch_bounds__(256)
void k_iter(const float* __restrict__ I1, const float* __restrict__ I2,
            const double* __restrict__ p_in, const int* __restrict__ done_in,
            const double* __restrict__ S_in, double* __restrict__ S_out,
            double* __restrict__ p_out_g, int* __restrict__ done_out_g,
            int first) {
    __shared__ lf4 SMEM[NR2 * PITCH2];      // 18048 B; aliased as reduction scratch
    __shared__ double Ssum[NACC];
    __shared__ double pbc[NPAR];
    __shared__ int dbc;
    const int tid = threadIdx.x;
    const int b = blockIdx.y;

    if (!first) {
        if (tid < NACC) {
            double a0 = 0.0, a1 = 0.0;
#pragma unroll
            for (int k = 0; k < KB_; k += 2) {
                a0 += S_in[((size_t)(k * BB + b)) * SPS + tid];
                a1 += S_in[((size_t)((k + 1) * BB + b)) * SPS + tid];
            }
            Ssum[tid] = a0 + a1;
        }
        __syncthreads();
    }
    if (tid == 0) {
        if (first) {
#pragma unroll
            for (int i = 0; i < NPAR; i++) pbc[i] = p_in[b * NPAR + i];
            dbc = done_in[b];
        } else {
            if (done_in[b]) {
#pragma unroll
                for (int i = 0; i < NPAR; i++) pbc[i] = p_in[b * NPAR + i];
                dbc = 1;
            } else {
                double pn[6]; int conv;
                solve6_fast(Ssum, p_in + b * NPAR, pn, &conv);
#pragma unroll
                for (int i = 0; i < NPAR; i++) pbc[i] = pn[i];
                dbc = conv;
            }
            if (blockIdx.x == 0) {
#pragma unroll
                for (int i = 0; i < NPAR; i++) p_out_g[b * NPAR + i] = pbc[i];
                done_out_g[b] = dbc;
            }
        }
    }
    __syncthreads();
    if (dbc) return;                        // frozen batch: S_out stays zero

    const int tix = blockIdx.x;             // 0..272
    const int rt = tix / 3, win = tix - rt * 3;
    const int y0 = 10 + rt * 4;             // rows y0..y0+3, all in [10,373]
    const int x0 = 10 + win * 128;
    const int W = (win == 2) ? 108 : 128;
    const int sx0 = x0 - 6;

    const double M00 = 1.0 + pbc[2], M01 = pbc[3], M02 = pbc[0];
    const double M10 = pbc[4], M11 = 1.0 + pbc[5], M12 = pbc[1];
    const float* I1b = I1 + (size_t)b * HWPIX * 3;
    const float* I2b = I2 + (size_t)b * HWPIX * 3;

    const double ygc = M10 * (double)(x0 + 64) + M11 * ((double)y0 + 1.5) + M12;
    const int r0 = (int)fmin(fmax(floor(ygc) - 3.0, -100000.0), 100000.0);

    // stage I2 rows r0..r0+7 (clamped) — one dwordx4 per element, const width
    for (int i = tid; i < NR2 * WS2C; i += 256) {
        const int r = i / WS2C, c = i - r * WS2C;     // compile-time divisor
        const int gr = min(max(r0 + r, 0), HH - 1);
        const int gc = min(sx0 + c, WW - 1);           // sx0 >= 4
        SMEM[r * PITCH2 + c] = ldpx3(I2b, gr * WW + gc);
    }
    __syncthreads();

    const int wid = tid >> 6, lane = tid & 63;
    const int y = y0 + wid;                 // wave-uniform row, <= 373
    const double Y = (double)y;
    const double Bx = M01 * Y + M02;
    const double By = M11 * Y + M12;

    double s[13];
#pragma unroll
    for (int i = 0; i < 13; i++) s[i] = 0.0;
    // s: 0=T0 1=T0X 2=T1 3=T1X 4=A 5=AX 6=AXX 7=B 8=BX 9=BXX 10=C 11=CX 12=CXX

#pragma unroll
    for (int step = 0; step < 2; step++) {
        const int col = lane + 64 * step;
        const int x = x0 + col;
        const double X = (double)x;
        const double xg = fma(M00, X, Bx);
        const double yg = fma(M10, X, By);
        const double gx = rint(xg), gy = rint(yg);   // half-to-even like jnp.round
        const bool ok = (col < W) &&
                        (gx >= (double)DEL && gx <= (double)(WW - DEL) &&
                         gy >= (double)DEL && gy <= (double)(HH - DEL));
        const double fx = floor(xg), fy = floor(yg);
        const int xi = (int)fx, yi = (int)fy;
        const float tx = (float)(xg - fx), ty = (float)(yg - fy);
        const int sxi = xi - sx0, syi = yi - r0;
        const bool inwin = ok && (sxi >= 1) && (sxi <= WS2C - 3) && (syi >= 1) && (syi <= NR2 - 3);

        float Iw[3];
        if (ok && !inwin) {
            bicubic3_fast(I2b, xg, yg, Iw);   // rare drift fallback
        } else {
            const int ssx = inwin ? sxi : 8;
            const int ssy = inwin ? syi : 2;
            bicubic3_lds(SMEM, ssx, ssy, tx, ty, Iw);
        }

        // I1 neighborhood via coalesced global vector loads (interior-clamped)
        const int xc = min(x, WW - DEL - 1);
        const int pixL = y * WW + xc;
        const float* c = I1b + pixL * 3;
        vf4 u0 = ldv4(c - 3);          // cl0 cl1 cl2 c0
        vf4 u1 = ldv4(c + 1);          // c1 c2 cr0 cr1
        float cr2 = c[5];
        vf4 uu = ldv4(c - WW * 3);     // cu
        vf4 ud = ldv4(c + WW * 3);     // cd

        const float cl[3] = {u0.x, u0.y, u0.z};
        const float cv[3] = {u0.w, u1.x, u1.y};
        const float cr[3] = {u1.z, u1.w, cr2};
        const float cu[3] = {uu.x, uu.y, uu.z};
        const float cd[3] = {ud.x, ud.y, ud.z};

        const float msk = ok ? 1.0f : 0.0f;
        float Af = 0.f, Bf = 0.f, Cf = 0.f, T0f = 0.f, T1f = 0.f;
#pragma unroll
        for (int ch = 0; ch < 3; ch++) {
            const float Ix = (cr[ch] - cl[ch]) * 0.5f;
            const float Iy = (cd[ch] - cu[ch]) * 0.5f;
            const float d = Iw[ch] - cv[ch];
            const float u = d * 20.0f;
            const float w = msk / sqrtf(fmaf(u, u, 1.0f));
            const float wd = w * d;
            T0f = fmaf(Ix, wd, T0f);
            T1f = fmaf(Iy, wd, T1f);
            const float wIx = w * Ix;
            Af = fmaf(wIx, Ix, Af);
            Bf = fmaf(wIx, Iy, Bf);
            Cf = fmaf(w * Iy, Iy, Cf);
        }
        const double T0 = (double)T0f, T1 = (double)T1f;
        const double A = (double)Af, Bd = (double)Bf, Cd = (double)Cf;
        const double XX = X * X;
        s[0] += T0;  s[1] = fma(T0, X, s[1]);
        s[2] += T1;  s[3] = fma(T1, X, s[3]);
        s[4] += A;   s[5] = fma(A, X, s[5]);   s[6] = fma(A, XX, s[6]);
        s[7] += Bd;  s[8] = fma(Bd, X, s[8]);  s[9] = fma(Bd, XX, s[9]);
        s[10] += Cd; s[11] = fma(Cd, X, s[11]); s[12] = fma(Cd, XX, s[12]);
    }

    // one shuffle fold (lane+32), then lanes 0..31 dump raw partials to LDS
#pragma unroll
    for (int i = 0; i < 13; i++) s[i] += __shfl_down(s[i], 32, 64);

    __syncthreads();                         // staged reads done; alias as scratch
    double* scr = (double*)SMEM;             // 4 waves x 32 lanes x 13 f64 = 13312 B
    if (lane < 32) {
        double* o = scr + ((size_t)(wid * 32 + lane)) * 13;
#pragma unroll
        for (int i = 0; i < 13; i++) o[i] = s[i];
    }
    __syncthreads();

    if (tid < NACC) {
        // component -> (s index, Y power)
        const int comp[NACC] = {0,1,0, 2,3,2, 4,5,4, 6,5,4, 7,8,7, 9,8,7, 10,11,10, 12,11,10};
        const int ypw[NACC]  = {0,0,1, 0,0,1, 0,0,1, 0,1,2, 0,0,1, 0,1,2, 0,0,1,   0,1,2};
        const int cix = comp[tid], pw = ypw[tid];
        double acc = 0.0;
        for (int w = 0; w < 4; w++) {
            const double* basep = scr + ((size_t)(w * 32)) * 13 + cix;
            double part = 0.0;
            for (int l = 0; l < 32; l++) part += basep[(size_t)l * 13];
            const double Yw = (double)(y0 + w);
            const double f = (pw == 0) ? 1.0 : ((pw == 1) ? Yw : Yw * Yw);
            acc = fma(f, part, acc);
        }
        const int bkt = blockIdx.x & (KB_ - 1);
        unsafeAtomicAdd(&S_out[((size_t)(bkt * BB + b)) * SPS + tid], acc);
    }
}

// 4-row x 128-col tiles over the FULL image; lane owns 2 consecutive px.
// Vectorized pair stores (dwordx4+dwordx2 per array). Prologue computes pf.
extern "C" __global__ __launch_bounds__(256)
void k_final_map(const float* __restrict__ I1, const float* __restrict__ I2,
                 const double* __restrict__ p_in, const int* __restrict__ done_in,
                 const double* __restrict__ S_in, double* __restrict__ pf_g,
                 float* __restrict__ DI_out, float* __restrict__ Iw_out,
                 double* __restrict__ Sf_part) {
    __shared__ lf4 I2S[NR2 * PITCH2];
    __shared__ double wsum[4][2];
    __shared__ double Ssum[NACC];
    __shared__ double pbc[NPAR];
    const int tid = threadIdx.x;
    const int b = blockIdx.y;

    if (tid < NACC) {
        double a0 = 0.0, a1 = 0.0;
#pragma unroll
        for (int k = 0; k < KB_; k += 2) {
            a0 += S_in[((size_t)(k * BB + b)) * SPS + tid];
            a1 += S_in[((size_t)((k + 1) * BB + b)) * SPS + tid];
        }
        Ssum[tid] = a0 + a1;
    }
    __syncthreads();
    if (tid == 0) {
        if (done_in[b]) {
#pragma unroll
            for (int i = 0; i < NPAR; i++) pbc[i] = p_in[b * NPAR + i];
        } else {
            double pn[6]; int conv;
            solve6_fast(Ssum, p_in + b * NPAR, pn, &conv);
#pragma unroll
            for (int i = 0; i < NPAR; i++) pbc[i] = pn[i];
        }
        if (blockIdx.x == 0) {
#pragma unroll
            for (int i = 0; i < NPAR; i++) pf_g[b * NPAR + i] = pbc[i];
        }
    }
    __syncthreads();

    const int tix = blockIdx.x;                 // 0..287
    const int rt = tix / 3, win = tix - rt * 3;
    const int y0 = rt * 4;
    const int x0 = win * 128;
    const int sx0 = x0 - 6;

    const double M00 = 1.0 + pbc[2], M01 = pbc[3], M02 = pbc[0];
    const double M10 = pbc[4], M11 = 1.0 + pbc[5], M12 = pbc[1];
    const float* I1b = I1 + (size_t)b * HWPIX * 3;
    const float* I2b = I2 + (size_t)b * HWPIX * 3;
    float* DIb = DI_out + (size_t)b * HWPIX * 3;
    float* Iwb = Iw_out + (size_t)b * HWPIX * 3;

    const double ygc = M10 * (double)(x0 + 64) + M11 * ((double)y0 + 1.5) + M12;
    const int r0 = (int)fmin(fmax(floor(ygc) - 3.0, -100000.0), 100000.0);

    for (int i = tid; i < NR2 * WS2C; i += 256) {
        const int r = i / WS2C, c = i - r * WS2C;
        const int gr = min(max(r0 + r, 0), HH - 1);    // clamped staging == clip-to-edge
        const int gc = min(max(sx0 + c, 0), WW - 1);
        I2S[r * PITCH2 + c] = ldpx3(I2b, gr * WW + gc);
    }
    __syncthreads();

    const int row = tid >> 6, lane = tid & 63;
    const int y = y0 + row;
    const int x1 = x0 + 2 * lane;               // even, 0..382
    const int pix1 = y * WW + x1;

    float Iwp[2][3];
    bool mp[2];
    double rho_s = 0.0, cnt_s = 0.0;

    // pair I1 center load (always in-bounds: last pair ends exactly at image end)
    const float* cbase = I1b + (size_t)pix1 * 3;
    const vf4 Ac = ldv4(cbase);                 // f..f+3
    const vf4 A2c = ldv4(cbase + 2);            // f+2..f+5

#pragma unroll
    for (int j = 0; j < 2; j++) {
        const int x = x1 + j;
        const double X = (double)x, Yd = (double)y;
        const double xg = fma(M00, X, fma(M01, Yd, M02));
        const double yg = fma(M10, X, fma(M11, Yd, M12));
        const double fx = floor(xg), fy = floor(yg);
        const int xi = (int)fx, yi = (int)fy;
        const float tx = (float)(xg - fx), ty = (float)(yg - fy);
        const int sxi = xi - sx0, syi = yi - r0;
        const bool inwin = (sxi >= 1) && (sxi <= WS2C - 3) && (syi >= 1) && (syi <= NR2 - 3);

        if (inwin) bicubic3_lds(I2S, sxi, syi, tx, ty, Iwp[j]);
        else       bicubic3_gen(I2b, xg, yg, Iwp[j]);

        const bool v1 = (x >= DEL) && (x < WW - DEL) && (y >= DEL) && (y < HH - DEL);
        const double gx = rint(xg), gy = rint(yg);
        const bool wm = (gx >= (double)DEL && gx <= (double)(WW - DEL) &&
                         gy >= (double)DEL && gy <= (double)(HH - DEL));
        mp[j] = v1 && wm;
    }

    // vectorized Iw store (pair = 6 floats)
    {
        float* wp = Iwb + (size_t)pix1 * 3;
        *(uvf4*)wp = (vf4){Iwp[0][0], Iwp[0][1], Iwp[0][2], Iwp[1][0]};
        *(f2v*)(wp + 4) = (f2v){Iwp[1][1], Iwp[1][2]};
    }
    // DI pair + rho
    {
        const float cv1[3] = {Ac.x, Ac.y, Ac.z};
        const float cv2[3] = {Ac.w, A2c.z, A2c.w};
        float dv[6];
#pragma unroll
        for (int ch = 0; ch < 3; ch++) {
            const float d1 = mp[0] ? (Iwp[0][ch] - cv1[ch]) : 0.0f;
            const float d2 = mp[1] ? (Iwp[1][ch] - cv2[ch]) : 0.0f;
            dv[ch] = d1;
            dv[3 + ch] = d2;
            if (mp[0]) {
                const float u = d1 * 20.0f;
                rho_s += (double)(0.005f * (sqrtf(fmaf(u, u, 1.0f)) - 1.0f));
            }
            if (mp[1]) {
                const float u = d2 * 20.0f;
                rho_s += (double)(0.005f * (sqrtf(fmaf(u, u, 1.0f)) - 1.0f));
            }
        }
        if (mp[0]) cnt_s += 3.0;
        if (mp[1]) cnt_s += 3.0;
        float* dp_ = DIb + (size_t)pix1 * 3;
        *(uvf4*)dp_ = (vf4){dv[0], dv[1], dv[2], dv[3]};
        *(f2v*)(dp_ + 4) = (f2v){dv[4], dv[5]};
    }

#pragma unroll
    for (int off = 32; off >= 1; off >>= 1) {
        rho_s += __shfl_down(rho_s, off, 64);
        cnt_s += __shfl_down(cnt_s, off, 64);
    }
    if (lane == 0) { wsum[row][0] = rho_s; wsum[row][1] = cnt_s; }
    __syncthreads();
    if (tid < 2) {
        double sv = wsum[0][tid] + wsum[1][tid] + wsum[2][tid] + wsum[3][tid];
        const int bkt = blockIdx.x & (KB_ - 1);
        unsafeAtomicAdd(&Sf_part[((size_t)(bkt * BB + b)) * 4 + tid], sv);
    }
}

extern "C" __global__ void k_finish(const double* __restrict__ p_fin,
                                    const double* __restrict__ Sf_part,
                                    float* __restrict__ out) {
    const int tid = threadIdx.x;  // 64 threads
    if (tid < BB * NPAR) out[tid] = (float)p_fin[tid];           // pf
    if (tid >= 48 && tid < 48 + BB) {
        const int b = tid - 48;
        double rs = 0.0, cs = 0.0;
#pragma unroll
        for (int k = 0; k < KB_; k++) {
            rs += Sf_part[((size_t)(k * BB + b)) * 4 + 0];
            cs += Sf_part[((size_t)(k * BB + b)) * 4 + 1];
        }
        out[48 + b] = (float)(rs / fmax(cs, 1.0));               // err
    }
}

extern "C" void kernel_launch(void* const* d_in, const int* in_sizes, int n_in,
                              void* d_out, int out_size, void* d_ws, size_t ws_size,
                              hipStream_t stream) {
    const float* I1 = (const float*)d_in[0];
    const float* I2 = (const float*)d_in[1];
    const float* p0 = (const float*)d_in[2];
    float* out = (float*)d_out;

    // ws layout (8B-aligned):
    // [0)      p_store    (MAXIT+1)*48 doubles = 4992 B   (p[it]; p[12]=pf)
    // [4992)   done       (MAXIT+1)*8 ints     = 416 B
    // [5408)   S_part_all MAXIT*8*8*32 doubles = 196608 B (bucketed, line-padded)
    // [202016) Sf_part    8*8*4 doubles        = 2048 B
    double* p_store = (double*)d_ws;
    int* done_flags = (int*)((char*)d_ws + 4992);
    double* S_part_all = (double*)((char*)d_ws + 5408);
    double* Sf_part = (double*)((char*)d_ws + 202016);

    k_init<<<8, 256, 0, stream>>>(p0, p_store, done_flags, S_part_all, Sf_part);

    const size_t SIT = (size_t)KB_ * BB * SPS;   // doubles per iteration
    dim3 gridI(NRT4 * 3, BB), blkI(256);
    for (int it = 0; it < MAXIT; it++) {
        const int first = (it == 0) ? 1 : 0;
        const double* p_in = p_store + (size_t)(first ? 0 : (it - 1)) * BB * NPAR;
        const int* d_in_f = done_flags + (first ? 0 : (it - 1)) * BB;
        const double* S_in = S_part_all + (size_t)(first ? 0 : (it - 1)) * SIT; // unused if first
        k_iter<<<gridI, blkI, 0, stream>>>(I1, I2, p_in, d_in_f, S_in,
                                           S_part_all + (size_t)it * SIT,
                                           p_store + (size_t)it * BB * NPAR,
                                           done_flags + it * BB, first);
    }
    // k_iter(11) wrote p(11)/done(11); k_final_map computes p(12)=pf from buckets of it=11.
    float* DI_out = out + 56;
    float* Iw_out = out + 56 + (size_t)BB * HWPIX * 3;
    dim3 gridF(96 * 3, BB), blkF(256);
    k_final_map<<<gridF, blkF, 0, stream>>>(I1, I2,
                                            p_store + (size_t)11 * BB * NPAR,
                                            done_flags + 11 * BB,
                                            S_part_all + (size_t)11 * SIT,
                                            p_store + (size_t)MAXIT * BB * NPAR,
                                            DI_out, Iw_out, Sf_part);
    k_finish<<<1, 64, 0, stream>>>(p_store + (size_t)MAXIT * BB * NPAR, Sf_part, out);
}

// Round 16
// 423.373 us; speedup vs baseline: 1.0789x; 1.0296x over previous
//
#include <hip/hip_runtime.h>
#include <math.h>

#define BB 8
#define HH 384
#define WW 384
#define NPAR 6
#define DEL 10
#define MAXIT 12
#define NACC 24
#define HWPIX (HH*WW)
#define NRT4 91                 // 4-row bands covering rows 10..373 exactly
#define PITCH2 195              // k_iter staged I2 pitch (194 used)
#define NR2 8                   // staged I2 rows
#define WS2C 194                // k_iter staging width = 182 + 12 (compile-time)
#define WIN 182                 // k_iter window cols (2 windows: 10..191, 192..373)
#define PITCHF 141              // k_final_map staged pitch (140 used)
#define WSF 140                 // k_final_map staging width (128 + 12)
#define KB_ 8                   // atomic buckets (blockIdx.x & 7)
#define SPS 32                  // doubles per (bucket,b) slot (256 B, line-padded)

typedef float vf4 __attribute__((ext_vector_type(4)));
typedef vf4 uvf4 __attribute__((aligned(4)));      // 4B-aligned global dwordx4
typedef float f2v __attribute__((ext_vector_type(2), aligned(4)));
typedef float lf4 __attribute__((ext_vector_type(4)));  // 16B-aligned (LDS)

__device__ __forceinline__ vf4 ldv4(const float* p) { return *(const uvf4*)p; }

// One-instruction staged-pixel load: dwordx4 covering this pixel's 3 floats.
// Tail guard: last pixel uses a shifted load to avoid a 4B OOB read.
__device__ __forceinline__ lf4 ldpx3(const float* __restrict__ Ib, int pixoff) {
    const int fo = pixoff * 3;
    if (fo + 4 <= HWPIX * 3) {
        vf4 v = ldv4(Ib + fo);
        return (lf4){v.x, v.y, v.z, 0.f};
    }
    vf4 v = ldv4(Ib + fo - 1);
    return (lf4){v.y, v.z, v.w, 0.f};
}

__device__ __forceinline__ float cubicw(float s) {
    s = fabsf(s);
    float s2 = s * s, s3 = s2 * s;
    float w1 = 1.5f * s3 - 2.5f * s2 + 1.0f;
    float w2 = -0.5f * s3 + 2.5f * s2 - 4.0f * s + 2.0f;
    return (s <= 1.0f) ? w1 : ((s < 2.0f) ? w2 : 0.0f);
}

// global fast-path bicubic (taps guaranteed in-bounds; drift fallback in k_iter)
__device__ __forceinline__ void bicubic3_fast(const float* __restrict__ Ib, double xg, double yg, float Iw[3]) {
    double fx = floor(xg), fy = floor(yg);
    float tx = (float)(xg - fx), ty = (float)(yg - fy);
    int xi = (int)fx, yi = (int)fy;
    float wx[4], wyv[4];
#pragma unroll
    for (int k = 0; k < 4; k++) { wx[k] = cubicw(tx - (float)(k - 1)); wyv[k] = cubicw(ty - (float)(k - 1)); }
    Iw[0] = 0.f; Iw[1] = 0.f; Iw[2] = 0.f;
    const float* base = Ib + (yi - 1) * (WW * 3) + (xi - 1) * 3;
#pragma unroll
    for (int j = 0; j < 4; j++) {
        const float* r = base + j * (WW * 3);
        vf4 v0 = ldv4(r), v1 = ldv4(r + 4), v2 = ldv4(r + 8);
        float r0 = fmaf(wx[0], v0.x, 0.f); r0 = fmaf(wx[1], v0.w, r0); r0 = fmaf(wx[2], v1.z, r0); r0 = fmaf(wx[3], v2.y, r0);
        float r1 = fmaf(wx[0], v0.y, 0.f); r1 = fmaf(wx[1], v1.x, r1); r1 = fmaf(wx[2], v1.w, r1); r1 = fmaf(wx[3], v2.z, r1);
        float r2 = fmaf(wx[0], v0.z, 0.f); r2 = fmaf(wx[1], v1.y, r2); r2 = fmaf(wx[2], v2.x, r2); r2 = fmaf(wx[3], v2.w, r2);
        Iw[0] = fmaf(wyv[j], r0, Iw[0]);
        Iw[1] = fmaf(wyv[j], r1, Iw[1]);
        Iw[2] = fmaf(wyv[j], r2, Iw[2]);
    }
}

// general bicubic with clip-to-edge (k_final_map fallback)
__device__ __forceinline__ void bicubic3_gen(const float* __restrict__ Ib, double xg, double yg, float Iw[3]) {
    double fx = floor(xg), fy = floor(yg);
    int xi = (int)fx, yi = (int)fy;
    float tx = (float)(xg - fx), ty = (float)(yg - fy);
    float wx[4], wyv[4];
    int xx[4], yy[4];
#pragma unroll
    for (int k = 0; k < 4; k++) {
        wx[k] = cubicw(tx - (float)(k - 1)); wyv[k] = cubicw(ty - (float)(k - 1));
        xx[k] = min(max(xi + k - 1, 0), WW - 1);
        yy[k] = min(max(yi + k - 1, 0), HH - 1);
    }
    Iw[0] = 0.f; Iw[1] = 0.f; Iw[2] = 0.f;
#pragma unroll
    for (int j = 0; j < 4; j++) {
        const float* row = Ib + yy[j] * (WW * 3);
        float r0 = 0.f, r1 = 0.f, r2 = 0.f;
#pragma unroll
        for (int k = 0; k < 4; k++) {
            const float* q = row + xx[k] * 3;
            r0 = fmaf(wx[k], q[0], r0); r1 = fmaf(wx[k], q[1], r1); r2 = fmaf(wx[k], q[2], r2);
        }
        Iw[0] = fmaf(wyv[j], r0, Iw[0]);
        Iw[1] = fmaf(wyv[j], r1, Iw[1]);
        Iw[2] = fmaf(wyv[j], r2, Iw[2]);
    }
}

// LDS bicubic from float4-padded staged tile (identical fma order); pitch param
template<int P>
__device__ __forceinline__ void bicubic3_lds(const lf4* __restrict__ T, int ssx, int ssy,
                                             float tx, float ty, float Iw[3]) {
    float wx[4], wyv[4];
#pragma unroll
    for (int k = 0; k < 4; k++) { wx[k] = cubicw(tx - (float)(k - 1)); wyv[k] = cubicw(ty - (float)(k - 1)); }
    Iw[0] = 0.f; Iw[1] = 0.f; Iw[2] = 0.f;
    const lf4* bp = T + (ssy - 1) * P + (ssx - 1);
#pragma unroll
    for (int j = 0; j < 4; j++) {
        lf4 t0 = bp[j * P + 0], t1 = bp[j * P + 1], t2 = bp[j * P + 2], t3 = bp[j * P + 3];
        float r0 = fmaf(wx[0], t0.x, 0.f); r0 = fmaf(wx[1], t1.x, r0); r0 = fmaf(wx[2], t2.x, r0); r0 = fmaf(wx[3], t3.x, r0);
        float r1 = fmaf(wx[0], t0.y, 0.f); r1 = fmaf(wx[1], t1.y, r1); r1 = fmaf(wx[2], t2.y, r1); r1 = fmaf(wx[3], t3.y, r1);
        float r2 = fmaf(wx[0], t0.z, 0.f); r2 = fmaf(wx[1], t1.z, r2); r2 = fmaf(wx[2], t2.z, r2); r2 = fmaf(wx[3], t3.z, r2);
        Iw[0] = fmaf(wyv[j], r0, Iw[0]);
        Iw[1] = fmaf(wyv[j], r1, Iw[1]);
        Iw[2] = fmaf(wyv[j], r2, Iw[2]);
    }
}

// Registers-only 6x6 SPD solve + affine compose. Fully unrolled Cholesky.
__device__ __forceinline__
void solve6_fast(const double* __restrict__ Sb, const double* __restrict__ pc,
                 double pn[6], int* convp) {
    const double b0 = Sb[0], b1 = Sb[3], b2 = Sb[1], b3 = Sb[2], b4 = Sb[4], b5 = Sb[5];
    const double h00 = Sb[6]  + 1e-6, h01 = Sb[12], h02 = Sb[7],  h03 = Sb[8],  h04 = Sb[13], h05 = Sb[14];
    const double h11 = Sb[18] + 1e-6, h12 = Sb[13], h13 = Sb[14], h14 = Sb[19], h15 = Sb[20];
    const double h22 = Sb[9]  + 1e-6, h23 = Sb[10], h24 = Sb[15], h25 = Sb[16];
    const double h33 = Sb[11] + 1e-6, h34 = Sb[16], h35 = Sb[17];
    const double h44 = Sb[21] + 1e-6, h45 = Sb[22];
    const double h55 = Sb[23] + 1e-6;

    const double l00 = sqrt(h00);
    const double i0 = 1.0 / l00;
    const double l10 = h01 * i0, l20 = h02 * i0, l30 = h03 * i0, l40 = h04 * i0, l50 = h05 * i0;
    const double l11 = sqrt(h11 - l10 * l10);
    const double i1 = 1.0 / l11;
    const double l21 = (h12 - l20 * l10) * i1;
    const double l31 = (h13 - l30 * l10) * i1;
    const double l41 = (h14 - l40 * l10) * i1;
    const double l51 = (h15 - l50 * l10) * i1;
    const double l22 = sqrt(h22 - l20 * l20 - l21 * l21);
    const double i2 = 1.0 / l22;
    const double l32 = (h23 - l30 * l20 - l31 * l21) * i2;
    const double l42 = (h24 - l40 * l20 - l41 * l21) * i2;
    const double l52 = (h25 - l50 * l20 - l51 * l21) * i2;
    const double l33 = sqrt(h33 - l30 * l30 - l31 * l31 - l32 * l32);
    const double i3 = 1.0 / l33;
    const double l43 = (h34 - l40 * l30 - l41 * l31 - l42 * l32) * i3;
    const double l53 = (h35 - l50 * l30 - l51 * l31 - l52 * l32) * i3;
    const double l44 = sqrt(h44 - l40 * l40 - l41 * l41 - l42 * l42 - l43 * l43);
    const double i4 = 1.0 / l44;
    const double l54 = (h45 - l50 * l40 - l51 * l41 - l52 * l42 - l53 * l43) * i4;
    const double l55 = sqrt(h55 - l50 * l50 - l51 * l51 - l52 * l52 - l53 * l53 - l54 * l54);
    const double i5 = 1.0 / l55;

    const double y0 = b0 * i0;
    const double y1 = (b1 - l10 * y0) * i1;
    const double y2 = (b2 - l20 * y0 - l21 * y1) * i2;
    const double y3 = (b3 - l30 * y0 - l31 * y1 - l32 * y2) * i3;
    const double y4 = (b4 - l40 * y0 - l41 * y1 - l42 * y2 - l43 * y3) * i4;
    const double y5 = (b5 - l50 * y0 - l51 * y1 - l52 * y2 - l53 * y3 - l54 * y4) * i5;

    const double d5 = y5 * i5;
    const double d4 = (y4 - l54 * d5) * i4;
    const double d3 = (y3 - l43 * d4 - l53 * d5) * i3;
    const double d2 = (y2 - l32 * d3 - l42 * d4 - l52 * d5) * i2;
    const double d1 = (y1 - l21 * d2 - l31 * d3 - l41 * d4 - l51 * d5) * i1;
    const double d0 = (y0 - l10 * d1 - l20 * d2 - l30 * d3 - l40 * d4 - l50 * d5) * i0;

    const double nrm = sqrt(d0*d0 + d1*d1 + d2*d2 + d3*d3 + d4*d4 + d5*d5);
    *convp = (nrm < 1e-3) ? 1 : 0;

    const double m00 = 1.0 + pc[2], m01 = pc[3], m02 = pc[0];
    const double m10 = pc[4], m11 = 1.0 + pc[5], m12 = pc[1];
    const double q00 = 1.0 + d2, q01 = d3, q02 = d0;
    const double q10 = d4, q11 = 1.0 + d5, q12 = d1;
    const double det = q00 * q11 - q01 * q10;
    const double j00 = q11 / det, j01 = -q01 / det;
    const double j10 = -q10 / det, j11 = q00 / det;
    const double jt0 = -(j00 * q02 + j01 * q12);
    const double jt1 = -(j10 * q02 + j11 * q12);
    const double n00 = m00 * j00 + m01 * j10;
    const double n01 = m00 * j01 + m01 * j11;
    const double n02 = m00 * jt0 + m01 * jt1 + m02;
    const double n10 = m10 * j00 + m11 * j10;
    const double n11 = m10 * j01 + m11 * j11;
    const double n12 = m10 * jt0 + m11 * jt1 + m12;
    pn[0] = n02;
    pn[1] = n12;
    pn[2] = n00 - 1.0;
    pn[3] = n01;
    pn[4] = n10;
    pn[5] = n11 - 1.0;
}

extern "C" __global__ __launch_bounds__(256)
void k_init(const float* __restrict__ p0, double* __restrict__ p_store,
            int* __restrict__ done0, double* __restrict__ S_part_all,
            double* __restrict__ Sf_part) {
    const int idx = blockIdx.x * 256 + threadIdx.x;
    const int n = MAXIT * KB_ * BB * SPS;          // 24576 doubles
    for (int i = idx; i < n; i += gridDim.x * 256) S_part_all[i] = 0.0;
    if (blockIdx.x == 0) {
        const int tid = threadIdx.x;
        if (tid < KB_ * BB * 4) Sf_part[tid] = 0.0;      // 256 doubles
        if (tid < BB * NPAR) p_store[tid] = (double)p0[tid];
        if (tid < BB) done0[tid] = 0;
    }
}

// 4-row x 182-col tile (2 windows/band -> 1456 blocks <= 1536 co-resident at
// 6 blocks/CU: SINGLE dispatch round; R15's 2184 blocks needed two rounds and
// every pipe sat <35% busy). Wave owns row y0+w; 3 col-steps of 64 lanes.
extern "C" __global__ __launch_bounds__(256)
void k_iter(const float* __restrict__ I1, const float* __restrict__ I2,
            const double* __restrict__ p_in, const int* __restrict__ done_in,
            const double* __restrict__ S_in, double* __restrict__ S_out,
            double* __restrict__ p_out_g, int* __restrict__ done_out_g,
            int first) {
    __shared__ lf4 SMEM[NR2 * PITCH2];      // 24960 B; aliased as reduction scratch
    __shared__ double Ssum[NACC];
    __shared__ double pbc[NPAR];
    __shared__ int dbc;
    const int tid = threadIdx.x;
    const int b = blockIdx.y;

    if (!first) {
        if (tid < NACC) {
            double a0 = 0.0, a1 = 0.0;
#pragma unroll
            for (int k = 0; k < KB_; k += 2) {
                a0 += S_in[((size_t)(k * BB + b)) * SPS + tid];
                a1 += S_in[((size_t)((k + 1) * BB + b)) * SPS + tid];
            }
            Ssum[tid] = a0 + a1;
        }
        __syncthreads();
    }
    if (tid == 0) {
        if (first) {
#pragma unroll
            for (int i = 0; i < NPAR; i++) pbc[i] = p_in[b * NPAR + i];
            dbc = done_in[b];
        } else {
            if (done_in[b]) {
#pragma unroll
                for (int i = 0; i < NPAR; i++) pbc[i] = p_in[b * NPAR + i];
                dbc = 1;
            } else {
                double pn[6]; int conv;
                solve6_fast(Ssum, p_in + b * NPAR, pn, &conv);
#pragma unroll
                for (int i = 0; i < NPAR; i++) pbc[i] = pn[i];
                dbc = conv;
            }
            if (blockIdx.x == 0) {
#pragma unroll
                for (int i = 0; i < NPAR; i++) p_out_g[b * NPAR + i] = pbc[i];
                done_out_g[b] = dbc;
            }
        }
    }
    __syncthreads();
    if (dbc) return;                        // frozen batch: S_out stays zero

    const int tix = blockIdx.x;             // 0..181
    const int rt = tix >> 1, win = tix & 1;
    const int y0 = 10 + rt * 4;             // rows y0..y0+3, all in [10,373]
    const int x0 = 10 + win * WIN;          // 10 or 192; cols 0..181
    const int sx0 = x0 - 6;                 // >= 4

    const double M00 = 1.0 + pbc[2], M01 = pbc[3], M02 = pbc[0];
    const double M10 = pbc[4], M11 = 1.0 + pbc[5], M12 = pbc[1];
    const float* I1b = I1 + (size_t)b * HWPIX * 3;
    const float* I2b = I2 + (size_t)b * HWPIX * 3;

    const double ygc = M10 * (double)(x0 + 91) + M11 * ((double)y0 + 1.5) + M12;
    const int r0 = (int)fmin(fmax(floor(ygc) - 3.0, -100000.0), 100000.0);

    // stage I2 rows r0..r0+7 (clamped) — one dwordx4 per element, const width
    for (int i = tid; i < NR2 * WS2C; i += 256) {
        const int r = i / WS2C, c = i - r * WS2C;     // compile-time divisor
        const int gr = min(max(r0 + r, 0), HH - 1);
        const int gc = min(sx0 + c, WW - 1);
        SMEM[r * PITCH2 + c] = ldpx3(I2b, gr * WW + gc);
    }
    __syncthreads();

    const int wid = tid >> 6, lane = tid & 63;
    const int y = y0 + wid;                 // wave-uniform row, <= 373
    const double Y = (double)y;
    const double Bx = M01 * Y + M02;
    const double By = M11 * Y + M12;

    double s[13];
#pragma unroll
    for (int i = 0; i < 13; i++) s[i] = 0.0;
    // s: 0=T0 1=T0X 2=T1 3=T1X 4=A 5=AX 6=AXX 7=B 8=BX 9=BXX 10=C 11=CX 12=CXX

#pragma unroll
    for (int step = 0; step < 3; step++) {
        const int col = lane + 64 * step;   // 0..191; masked at WIN=182
        const int x = x0 + col;
        const double X = (double)x;
        const double xg = fma(M00, X, Bx);
        const double yg = fma(M10, X, By);
        const double gx = rint(xg), gy = rint(yg);   // half-to-even like jnp.round
        const bool ok = (col < WIN) &&
                        (gx >= (double)DEL && gx <= (double)(WW - DEL) &&
                         gy >= (double)DEL && gy <= (double)(HH - DEL));
        const double fx = floor(xg), fy = floor(yg);
        const int xi = (int)fx, yi = (int)fy;
        const float tx = (float)(xg - fx), ty = (float)(yg - fy);
        const int sxi = xi - sx0, syi = yi - r0;
        const bool inwin = ok && (sxi >= 1) && (sxi <= WS2C - 3) && (syi >= 1) && (syi <= NR2 - 3);

        float Iw[3];
        if (ok && !inwin) {
            bicubic3_fast(I2b, xg, yg, Iw);   // rare drift fallback
        } else {
            const int ssx = inwin ? sxi : 8;
            const int ssy = inwin ? syi : 2;
            bicubic3_lds<PITCH2>(SMEM, ssx, ssy, tx, ty, Iw);
        }

        // I1 neighborhood via coalesced global vector loads (interior-clamped)
        const int xc = min(x, WW - DEL - 1);
        const int pixL = y * WW + xc;
        const float* c = I1b + pixL * 3;
        vf4 u0 = ldv4(c - 3);          // cl0 cl1 cl2 c0
        vf4 u1 = ldv4(c + 1);          // c1 c2 cr0 cr1
        float cr2 = c[5];
        vf4 uu = ldv4(c - WW * 3);     // cu
        vf4 ud = ldv4(c + WW * 3);     // cd

        const float cl[3] = {u0.x, u0.y, u0.z};
        const float cv[3] = {u0.w, u1.x, u1.y};
        const float cr[3] = {u1.z, u1.w, cr2};
        const float cu[3] = {uu.x, uu.y, uu.z};
        const float cd[3] = {ud.x, ud.y, ud.z};

        const float msk = ok ? 1.0f : 0.0f;
        float Af = 0.f, Bf = 0.f, Cf = 0.f, T0f = 0.f, T1f = 0.f;
#pragma unroll
        for (int ch = 0; ch < 3; ch++) {
            const float Ix = (cr[ch] - cl[ch]) * 0.5f;
            const float Iy = (cd[ch] - cu[ch]) * 0.5f;
            const float d = Iw[ch] - cv[ch];
            const float u = d * 20.0f;
            const float w = msk / sqrtf(fmaf(u, u, 1.0f));
            const float wd = w * d;
            T0f = fmaf(Ix, wd, T0f);
            T1f = fmaf(Iy, wd, T1f);
            const float wIx = w * Ix;
            Af = fmaf(wIx, Ix, Af);
            Bf = fmaf(wIx, Iy, Bf);
            Cf = fmaf(w * Iy, Iy, Cf);
        }
        const double T0 = (double)T0f, T1 = (double)T1f;
        const double A = (double)Af, Bd = (double)Bf, Cd = (double)Cf;
        const double XX = X * X;
        s[0] += T0;  s[1] = fma(T0, X, s[1]);
        s[2] += T1;  s[3] = fma(T1, X, s[3]);
        s[4] += A;   s[5] = fma(A, X, s[5]);   s[6] = fma(A, XX, s[6]);
        s[7] += Bd;  s[8] = fma(Bd, X, s[8]);  s[9] = fma(Bd, XX, s[9]);
        s[10] += Cd; s[11] = fma(Cd, X, s[11]); s[12] = fma(Cd, XX, s[12]);
    }

    // one shuffle fold (lane+32), then lanes 0..31 dump raw partials to LDS
#pragma unroll
    for (int i = 0; i < 13; i++) s[i] += __shfl_down(s[i], 32, 64);

    __syncthreads();                         // staged reads done; alias as scratch
    double* scr = (double*)SMEM;             // 4 waves x 32 lanes x 13 f64 = 13312 B
    if (lane < 32) {
        double* o = scr + ((size_t)(wid * 32 + lane)) * 13;
#pragma unroll
        for (int i = 0; i < 13; i++) o[i] = s[i];
    }
    __syncthreads();

    if (tid < NACC) {
        // component -> (s index, Y power)
        const int comp[NACC] = {0,1,0, 2,3,2, 4,5,4, 6,5,4, 7,8,7, 9,8,7, 10,11,10, 12,11,10};
        const int ypw[NACC]  = {0,0,1, 0,0,1, 0,0,1, 0,1,2, 0,0,1, 0,1,2, 0,0,1,   0,1,2};
        const int cix = comp[tid], pw = ypw[tid];
        double acc = 0.0;
        for (int w = 0; w < 4; w++) {
            const double* basep = scr + ((size_t)(w * 32)) * 13 + cix;
            double part = 0.0;
            for (int l = 0; l < 32; l++) part += basep[(size_t)l * 13];
            const double Yw = (double)(y0 + w);
            const double f = (pw == 0) ? 1.0 : ((pw == 1) ? Yw : Yw * Yw);
            acc = fma(f, part, acc);
        }
        const int bkt = blockIdx.x & (KB_ - 1);
        unsafeAtomicAdd(&S_out[((size_t)(bkt * BB + b)) * SPS + tid], acc);
    }
}

// 4-row x 128-col tiles over the FULL image; lane owns 2 consecutive px.
// Vectorized pair stores (dwordx4+dwordx2 per array). Prologue computes pf.
extern "C" __global__ __launch_bounds__(256)
void k_final_map(const float* __restrict__ I1, const float* __restrict__ I2,
                 const double* __restrict__ p_in, const int* __restrict__ done_in,
                 const double* __restrict__ S_in, double* __restrict__ pf_g,
                 float* __restrict__ DI_out, float* __restrict__ Iw_out,
                 double* __restrict__ Sf_part) {
    __shared__ lf4 I2S[NR2 * PITCHF];
    __shared__ double wsum[4][2];
    __shared__ double Ssum[NACC];
    __shared__ double pbc[NPAR];
    const int tid = threadIdx.x;
    const int b = blockIdx.y;

    if (tid < NACC) {
        double a0 = 0.0, a1 = 0.0;
#pragma unroll
        for (int k = 0; k < KB_; k += 2) {
            a0 += S_in[((size_t)(k * BB + b)) * SPS + tid];
            a1 += S_in[((size_t)((k + 1) * BB + b)) * SPS + tid];
        }
        Ssum[tid] = a0 + a1;
    }
    __syncthreads();
    if (tid == 0) {
        if (done_in[b]) {
#pragma unroll
            for (int i = 0; i < NPAR; i++) pbc[i] = p_in[b * NPAR + i];
        } else {
            double pn[6]; int conv;
            solve6_fast(Ssum, p_in + b * NPAR, pn, &conv);
#pragma unroll
            for (int i = 0; i < NPAR; i++) pbc[i] = pn[i];
        }
        if (blockIdx.x == 0) {
#pragma unroll
            for (int i = 0; i < NPAR; i++) pf_g[b * NPAR + i] = pbc[i];
        }
    }
    __syncthreads();

    const int tix = blockIdx.x;                 // 0..287
    const int rt = tix / 3, win = tix - rt * 3;
    const int y0 = rt * 4;
    const int x0 = win * 128;
    const int sx0 = x0 - 6;

    const double M00 = 1.0 + pbc[2], M01 = pbc[3], M02 = pbc[0];
    const double M10 = pbc[4], M11 = 1.0 + pbc[5], M12 = pbc[1];
    const float* I1b = I1 + (size_t)b * HWPIX * 3;
    const float* I2b = I2 + (size_t)b * HWPIX * 3;
    float* DIb = DI_out + (size_t)b * HWPIX * 3;
    float* Iwb = Iw_out + (size_t)b * HWPIX * 3;

    const double ygc = M10 * (double)(x0 + 64) + M11 * ((double)y0 + 1.5) + M12;
    const int r0 = (int)fmin(fmax(floor(ygc) - 3.0, -100000.0), 100000.0);

    for (int i = tid; i < NR2 * WSF; i += 256) {
        const int r = i / WSF, c = i - r * WSF;
        const int gr = min(max(r0 + r, 0), HH - 1);    // clamped staging == clip-to-edge
        const int gc = min(max(sx0 + c, 0), WW - 1);
        I2S[r * PITCHF + c] = ldpx3(I2b, gr * WW + gc);
    }
    __syncthreads();

    const int row = tid >> 6, lane = tid & 63;
    const int y = y0 + row;
    const int x1 = x0 + 2 * lane;               // even, 0..382
    const int pix1 = y * WW + x1;

    float Iwp[2][3];
    bool mp[2];
    double rho_s = 0.0, cnt_s = 0.0;

    // pair I1 center load (always in-bounds: last pair ends exactly at image end)
    const float* cbase = I1b + (size_t)pix1 * 3;
    const vf4 Ac = ldv4(cbase);                 // f..f+3
    const vf4 A2c = ldv4(cbase + 2);            // f+2..f+5

#pragma unroll
    for (int j = 0; j < 2; j++) {
        const int x = x1 + j;
        const double X = (double)x, Yd = (double)y;
        const double xg = fma(M00, X, fma(M01, Yd, M02));
        const double yg = fma(M10, X, fma(M11, Yd, M12));
        const double fx = floor(xg), fy = floor(yg);
        const int xi = (int)fx, yi = (int)fy;
        const float tx = (float)(xg - fx), ty = (float)(yg - fy);
        const int sxi = xi - sx0, syi = yi - r0;
        const bool inwin = (sxi >= 1) && (sxi <= WSF - 3) && (syi >= 1) && (syi <= NR2 - 3);

        if (inwin) bicubic3_lds<PITCHF>(I2S, sxi, syi, tx, ty, Iwp[j]);
        else       bicubic3_gen(I2b, xg, yg, Iwp[j]);

        const bool v1 = (x >= DEL) && (x < WW - DEL) && (y >= DEL) && (y < HH - DEL);
        const double gx = rint(xg), gy = rint(yg);
        const bool wm = (gx >= (double)DEL && gx <= (double)(WW - DEL) &&
                         gy >= (double)DEL && gy <= (double)(HH - DEL));
        mp[j] = v1 && wm;
    }

    // vectorized Iw store (pair = 6 floats)
    {
        float* wp = Iwb + (size_t)pix1 * 3;
        *(uvf4*)wp = (vf4){Iwp[0][0], Iwp[0][1], Iwp[0][2], Iwp[1][0]};
        *(f2v*)(wp + 4) = (f2v){Iwp[1][1], Iwp[1][2]};
    }
    // DI pair + rho
    {
        const float cv1[3] = {Ac.x, Ac.y, Ac.z};
        const float cv2[3] = {Ac.w, A2c.z, A2c.w};
        float dv[6];
#pragma unroll
        for (int ch = 0; ch < 3; ch++) {
            const float d1 = mp[0] ? (Iwp[0][ch] - cv1[ch]) : 0.0f;
            const float d2 = mp[1] ? (Iwp[1][ch] - cv2[ch]) : 0.0f;
            dv[ch] = d1;
            dv[3 + ch] = d2;
            if (mp[0]) {
                const float u = d1 * 20.0f;
                rho_s += (double)(0.005f * (sqrtf(fmaf(u, u, 1.0f)) - 1.0f));
            }
            if (mp[1]) {
                const float u = d2 * 20.0f;
                rho_s += (double)(0.005f * (sqrtf(fmaf(u, u, 1.0f)) - 1.0f));
            }
        }
        if (mp[0]) cnt_s += 3.0;
        if (mp[1]) cnt_s += 3.0;
        float* dp_ = DIb + (size_t)pix1 * 3;
        *(uvf4*)dp_ = (vf4){dv[0], dv[1], dv[2], dv[3]};
        *(f2v*)(dp_ + 4) = (f2v){dv[4], dv[5]};
    }

#pragma unroll
    for (int off = 32; off >= 1; off >>= 1) {
        rho_s += __shfl_down(rho_s, off, 64);
        cnt_s += __shfl_down(cnt_s, off, 64);
    }
    if (lane == 0) { wsum[row][0] = rho_s; wsum[row][1] = cnt_s; }
    __syncthreads();
    if (tid < 2) {
        double sv = wsum[0][tid] + wsum[1][tid] + wsum[2][tid] + wsum[3][tid];
        const int bkt = blockIdx.x & (KB_ - 1);
        unsafeAtomicAdd(&Sf_part[((size_t)(bkt * BB + b)) * 4 + tid], sv);
    }
}

extern "C" __global__ void k_finish(const double* __restrict__ p_fin,
                                    const double* __restrict__ Sf_part,
                                    float* __restrict__ out) {
    const int tid = threadIdx.x;  // 64 threads
    if (tid < BB * NPAR) out[tid] = (float)p_fin[tid];           // pf
    if (tid >= 48 && tid < 48 + BB) {
        const int b = tid - 48;
        double rs = 0.0, cs = 0.0;
#pragma unroll
        for (int k = 0; k < KB_; k++) {
            rs += Sf_part[((size_t)(k * BB + b)) * 4 + 0];
            cs += Sf_part[((size_t)(k * BB + b)) * 4 + 1];
        }
        out[48 + b] = (float)(rs / fmax(cs, 1.0));               // err
    }
}

extern "C" void kernel_launch(void* const* d_in, const int* in_sizes, int n_in,
                              void* d_out, int out_size, void* d_ws, size_t ws_size,
                              hipStream_t stream) {
    const float* I1 = (const float*)d_in[0];
    const float* I2 = (const float*)d_in[1];
    const float* p0 = (const float*)d_in[2];
    float* out = (float*)d_out;

    // ws layout (8B-aligned):
    // [0)      p_store    (MAXIT+1)*48 doubles = 4992 B   (p[it]; p[12]=pf)
    // [4992)   done       (MAXIT+1)*8 ints     = 416 B
    // [5408)   S_part_all MAXIT*8*8*32 doubles = 196608 B (bucketed, line-padded)
    // [202016) Sf_part    8*8*4 doubles        = 2048 B
    double* p_store = (double*)d_ws;
    int* done_flags = (int*)((char*)d_ws + 4992);
    double* S_part_all = (double*)((char*)d_ws + 5408);
    double* Sf_part = (double*)((char*)d_ws + 202016);

    k_init<<<8, 256, 0, stream>>>(p0, p_store, done_flags, S_part_all, Sf_part);

    const size_t SIT = (size_t)KB_ * BB * SPS;   // doubles per iteration
    dim3 gridI(NRT4 * 2, BB), blkI(256);         // 182 x 8 = 1456 blocks
    for (int it = 0; it < MAXIT; it++) {
        const int first = (it == 0) ? 1 : 0;
        const double* p_in = p_store + (size_t)(first ? 0 : (it - 1)) * BB * NPAR;
        const int* d_in_f = done_flags + (first ? 0 : (it - 1)) * BB;
        const double* S_in = S_part_all + (size_t)(first ? 0 : (it - 1)) * SIT; // unused if first
        k_iter<<<gridI, blkI, 0, stream>>>(I1, I2, p_in, d_in_f, S_in,
                                           S_part_all + (size_t)it * SIT,
                                           p_store + (size_t)it * BB * NPAR,
                                           done_flags + it * BB, first);
    }
    // k_iter(11) wrote p(11)/done(11); k_final_map computes p(12)=pf from buckets of it=11.
    float* DI_out = out + 56;
    float* Iw_out = out + 56 + (size_t)BB * HWPIX * 3;
    dim3 gridF(96 * 3, BB), blkF(256);
    k_final_map<<<gridF, blkF, 0, stream>>>(I1, I2,
                                            p_store + (size_t)11 * BB * NPAR,
                                            done_flags + 11 * BB,
                                            S_part_all + (size_t)11 * SIT,
                                            p_store + (size_t)MAXIT * BB * NPAR,
                                            DI_out, Iw_out, Sf_part);
    k_finish<<<1, 64, 0, stream>>>(p_store + (size_t)MAXIT * BB * NPAR, Sf_part, out);
}